// Round 1
// 340.932 us; speedup vs baseline: 1.1112x; 1.1112x over previous
//
#include <hip/hip_runtime.h>
#include <hip/hip_bf16.h>

#define B_ 8
#define H_ 128
#define W_ 256
#define PH 130          // H + 2 zero-pad rows
#define PW 258          // W + 2 zero-pad cols
#define NPIX (B_*64*H_*W_)

typedef short short8  __attribute__((ext_vector_type(8)));  // 8 bf16 (4 VGPRs)
typedef short short4v __attribute__((ext_vector_type(4)));  // 4 bf16 (8 B)
typedef float floatx4 __attribute__((ext_vector_type(4)));  // MFMA C/D

// ---------------------------------------------------------------------------
// Implicit-GEMM 3x3 SAME conv + bias + ReLU, bf16 MFMA 16x16x32, LDS-staged.
// Block = 256 thr = 4 waves; 4 output rows x 64 px x all Co. Wave r owns row.
// R5 changes vs R4 baseline:
//  * NCHW_IN: conv1 stages DIRECTLY from fp32 NCHW feat (fused transpose+cvt)
//    -> feat_to_nhwc + TF buffer + zero_border<64> eliminated entirely.
//    Staging: lane-per-pixel, 8 channel-strided fp32 loads (coalesced across
//    lanes: consecutive lanes = consecutive pixels), cvt->bf16, short8 to the
//    same swizzled slab slot. Zero-pad border via predicated select.
//  * AVG: conv4-m1 LOSS epilogue also reads feat0 at the identical tile
//    addresses and writes fused = 0.5*(f0+f1) -> fused_avg kernel eliminated.
//  * loss: 1/NPIX (exact 2^-24) folded into the per-block atomicAdd.
// ---------------------------------------------------------------------------
template<int Ci, int Co, bool LOSS, bool NCHW_IN, bool AVG>
__global__ __launch_bounds__(256)
void conv_mfma(const void* __restrict__ in_,                // bf16 padded NHWC, or fp32 NCHW if NCHW_IN
               const __hip_bfloat16* __restrict__ wt,       // [KC][Co][32] bf16
               const float* __restrict__ bias,
               __hip_bfloat16* __restrict__ outp,           // padded NHWC [B][PH][PW][Co]
               const float* __restrict__ ref,               // fp32 NCHW (LOSS only)
               const float* __restrict__ other,             // fp32 NCHW feat0 (AVG only)
               float* __restrict__ avg_out,                 // fp32 NCHW fused (AVG only)
               float* __restrict__ acc_out)
{
    constexpr int CC   = (Ci >= 32) ? Ci/32 : 1;
    constexpr int PXB  = Ci*2;                     // bytes per pixel in slab
    constexpr int NCB  = PXB/16;                   // 16B chunks per pixel
    constexpr int SLAB = 6*66*PXB;
    constexpr int NT   = Co/16;
    constexpr int GNT  = (NT >= 2) ? 2 : 1;        // nt-tiles per B-batch
    constexpr int NG   = NT / GNT;
    constexpr int EPIW = 64*(Co+8)*2;              // per-wave epilogue tile
    constexpr int RECB = 64*272*2;                 // LOSS rec tile [64co][4row][68px]
    constexpr int LDSZ = LOSS ? (RECB > SLAB ? RECB : SLAB)
                              : (4*EPIW > SLAB ? 4*EPIW : SLAB);
    __shared__ alignas(16) char slab[LDSZ + 32];
    __shared__ float wred[4];

    const int tid  = threadIdx.x;
    const int lane = tid & 63;
    const int wid  = tid >> 6;
    const int col  = lane & 15;
    const int quad = lane >> 4;
    const int w0   = blockIdx.x * 64;
    const int h0   = blockIdx.y * 4;
    const int bz   = blockIdx.z;
    const int r    = wid;

    floatx4 acc[4][NT];
#pragma unroll
    for (int mt = 0; mt < 4; ++mt)
#pragma unroll
        for (int nt = 0; nt < NT; ++nt)
            acc[mt][nt] = (floatx4)0.f;

    if constexpr (NCHW_IN) {
        // ---- stage slab straight from fp32 NCHW: rows h0-1..h0+4, cols
        // w0-1..w0+64 (zeros outside), all 64 ch. chunk k = cb*396 + pxl so a
        // wave's 64 lanes hit consecutive pixels (coalesced fp32 runs); the
        // swizzled ds_write_b128 lands 2 lanes/bank-group (free, m136).
        static_assert(Ci == 64, "NCHW staging is Ci=64 only");
        const float* src = (const float*)in_ + (size_t)bz * 64 * H_ * W_;
        for (int k = tid; k < 8*396; k += 256) {
            int cb  = k / 396;
            int pxl = k - cb*396;
            int row = pxl / 66;
            int pxc = pxl - row*66;
            int gh  = h0 + row - 1;
            int gw  = w0 + pxc - 1;
            bool ok = ((unsigned)gh < (unsigned)H_) && ((unsigned)gw < (unsigned)W_);
            const float* sp = src + (size_t)(cb*8)*(H_*W_)
                              + (size_t)(ok ? gh : 0)*W_ + (ok ? gw : 0);
            short8 v;
#pragma unroll
            for (int j = 0; j < 8; ++j) {
                float f = sp[(size_t)j*(H_*W_)];
                f = ok ? f : 0.f;
                v[j] = __builtin_bit_cast(short, __float2bfloat16(f));
            }
            *(short8*)(slab + pxl*PXB + ((cb ^ (pxl & 7)) << 4)) = v;
        }
    } else {
        // ---- stage slab from padded bf16 NHWC: coalesced 16B chunks.
        const __hip_bfloat16* inb = (const __hip_bfloat16*)in_ + (size_t)bz * PH * PW * Ci;
        for (int o = tid*16; o < SLAB; o += 4096) {
            int pxl = o / PXB;
            int row = pxl / 66;
            int pxc = pxl - row*66;
            int cb  = (o >> 4) & (NCB-1);
            short8 v = *(const short8*)(inb + ((size_t)(h0+row)*PW + (w0+pxc))*Ci + cb*8);
            *(short8*)(slab + pxl*PXB + ((cb ^ (pxl & (NCB-1))) << 4)) = v;
        }
    }
    __syncthreads();

    if constexpr (Ci >= 32) {
#pragma unroll
        for (int c2 = 0; c2 < CC; ++c2) {
#pragma unroll
            for (int g = 0; g < NG; ++g) {
                short8 bfr[9*GNT];     // batched independent B loads
#pragma unroll
                for (int t = 0; t < 9; ++t)
#pragma unroll
                    for (int j = 0; j < GNT; ++j)
                        bfr[t*GNT+j] = *(const short8*)(wt
                            + ((size_t)(c2*9+t)*Co + (g*GNT+j)*16 + col)*32 + quad*8);
#pragma unroll
                for (int t = 0; t < 9; ++t) {
                    const int dy = t/3, dx = t - (t/3)*3;
                    short8 a[4];
#pragma unroll
                    for (int mt = 0; mt < 4; ++mt) {
                        int px = (r+dy)*66 + mt*16 + col + dx;
                        a[mt] = *(const short8*)(slab + px*PXB
                                  + (((c2*4 + quad) ^ (px & (NCB-1))) << 4));
                    }
#pragma unroll
                    for (int j = 0; j < GNT; ++j)
#pragma unroll
                        for (int mt = 0; mt < 4; ++mt)
                            acc[mt][g*GNT+j] = __builtin_amdgcn_mfma_f32_16x16x32_bf16(
                                a[mt], bfr[t*GNT+j], acc[mt][g*GNT+j], 0, 0, 0);
                }
            }
        }
    } else {
        // Ci=16: K=32 packs 2 dx taps; half1 upper quads carry zero weights.
        short8 bfr[6*NT];
#pragma unroll
        for (int kc = 0; kc < 6; ++kc)
#pragma unroll
            for (int j = 0; j < NT; ++j)
                bfr[kc*NT+j] = *(const short8*)(wt
                    + ((size_t)kc*Co + j*16 + col)*32 + quad*8);
#pragma unroll
        for (int kc = 0; kc < 6; ++kc) {
            const int dy = kc >> 1, half = kc & 1;
            const int dxe = half ? 2 : (quad >> 1);
            short8 a[4];
#pragma unroll
            for (int mt = 0; mt < 4; ++mt) {
                int px = (r+dy)*66 + mt*16 + col + dxe;
                a[mt] = *(const short8*)(slab + px*PXB
                          + (((quad & 1) ^ (px & 1)) << 4));
            }
#pragma unroll
            for (int j = 0; j < NT; ++j)
#pragma unroll
                for (int mt = 0; mt < 4; ++mt)
                    acc[mt][j] = __builtin_amdgcn_mfma_f32_16x16x32_bf16(
                        a[mt], bfr[kc*NT+j], acc[mt][j], 0, 0, 0);
        }
    }

    if constexpr (!LOSS) {
        __syncthreads();
        char* rt = slab + wid * EPIW;     // per-wave [64 px][Co+8] bf16 tile
#pragma unroll
        for (int nt = 0; nt < NT; ++nt) {
            float bv = bias[nt*16 + col];
#pragma unroll
            for (int mt = 0; mt < 4; ++mt) {
#pragma unroll
                for (int rr = 0; rr < 4; ++rr) {
                    float v = acc[mt][nt][rr] + bv;
                    v = v > 0.f ? v : 0.f;
                    int px = mt*16 + quad*4 + rr;
                    *(__hip_bfloat16*)(rt + (px*(Co+8) + nt*16 + col)*2) =
                        __float2bfloat16(v);
                }
            }
        }
        char* grow = (char*)outp
            + (((size_t)bz*PH + (h0 + r + 1))*PW + (w0 + 1))*Co*2;
        constexpr int GB = 64*Co*2;
#pragma unroll
        for (int id = 0; id < GB/1024; ++id) {
            int o  = id*1024 + lane*16;
            int px = o / (Co*2);
            int cb = o - px*(Co*2);
            *(short8*)(grow + o) = *(const short8*)(rt + px*(Co+8)*2 + cb);
        }
    } else {
        // ---- rec -> LDS bf16 [co][row][68] (b64-aligned), barriered
        __syncthreads();                        // all slab reads complete
        __hip_bfloat16* rec = (__hip_bfloat16*)slab;
#pragma unroll
        for (int nt = 0; nt < NT; ++nt) {
            int co = nt*16 + col;
            float bv = bias[co];
#pragma unroll
            for (int mt = 0; mt < 4; ++mt) {
                short4v pk;
#pragma unroll
                for (int rr = 0; rr < 4; ++rr) {
                    float v = acc[mt][nt][rr] + bv;
                    v = v > 0.f ? v : 0.f;
                    pk[rr] = __builtin_bit_cast(short, __float2bfloat16(v));
                }
                *(short4v*)(rec + co*272 + r*68 + mt*16 + quad*4) = pk;
            }
        }
        __syncthreads();

        // ---- coalesced fp32 ref compare: 16 iters, 256B contiguous per co.
        // AVG: same tile addresses also cover feat0 -> fused = 0.5*(f0+f1).
        float lsum = 0.f;
        const float* refb = ref + (size_t)bz * 64 * H_ * W_;
#pragma unroll
        for (int i = 0; i < 16; ++i) {
            int row = i & 3, cg = i >> 2;
            int co  = cg*16 + wid*4 + quad;
            size_t off = ((size_t)co*H_ + h0 + row)*W_ + w0 + col*4;
            float4 f = *(const float4*)(refb + off);
            short4v pk = *(const short4v*)(rec + co*272 + row*68 + col*4);
            float d0 = f.x - __bfloat162float(__builtin_bit_cast(__hip_bfloat16, pk[0]));
            float d1 = f.y - __bfloat162float(__builtin_bit_cast(__hip_bfloat16, pk[1]));
            float d2 = f.z - __bfloat162float(__builtin_bit_cast(__hip_bfloat16, pk[2]));
            float d3 = f.w - __bfloat162float(__builtin_bit_cast(__hip_bfloat16, pk[3]));
            lsum += d0*d0 + d1*d1 + d2*d2 + d3*d3;
            if constexpr (AVG) {
                const float* othb = other + (size_t)bz * 64 * H_ * W_;
                float*       avgb = avg_out + (size_t)bz * 64 * H_ * W_;
                float4 g = *(const float4*)(othb + off);
                float4 o;
                o.x = 0.5f*(f.x + g.x);
                o.y = 0.5f*(f.y + g.y);
                o.z = 0.5f*(f.z + g.z);
                o.w = 0.5f*(f.w + g.w);
                *(float4*)(avgb + off) = o;
            }
        }
#pragma unroll
        for (int off = 32; off > 0; off >>= 1)
            lsum += __shfl_down(lsum, off, 64);
        if (lane == 0) wred[wid] = lsum;
        __syncthreads();
        if (tid == 0)      // 1/NPIX = 2^-24 exact: fold finalize into the atomic
            atomicAdd(acc_out, (wred[0] + wred[1] + wred[2] + wred[3])
                               * (1.0f / (float)NPIX));
    }
}

// ---------------------------------------------------------------------------
// Border-zero work item: pad cells of a padded NHWC buffer (772 px / image).
// ---------------------------------------------------------------------------
template<int C>
__device__ __forceinline__ void zb_item(__hip_bfloat16* buf, int idx)
{
    constexpr int CP = C/8;
    int cb   = idx % CP;
    int cell = (idx / CP) % 772;
    int img  = idx / (CP*772);
    int row, colp;
    if (cell < 258)      { row = 0;   colp = cell; }
    else if (cell < 516) { row = 129; colp = cell - 258; }
    else { int r2 = cell - 516; row = 1 + (r2 >> 1); colp = (r2 & 1) ? 257 : 0; }
    short8 z = (short8)0;
    *(short8*)(buf + (((size_t)img*PH + row)*PW + colp)*C + cb*8) = z;
}

// ---------------------------------------------------------------------------
// OIHW fp32 -> [KC][Co][32] bf16 B-operand work item. Ci>=32: kc = c2*9 + tap.
// Ci=16: kc = dy*2+half; dx slot 3 = zero.
// ---------------------------------------------------------------------------
template<int Ci, int Co>
__device__ __forceinline__ void wt_item(const float* __restrict__ w,
                                        __hip_bfloat16* __restrict__ wt, int idx)
{
    int kl = idx & 31;
    int co = (idx >> 5) % Co;
    int kc = idx / (32*Co);
    float val = 0.f;
    if constexpr (Ci >= 32) {
        int c2 = kc / 9, t = kc % 9;
        int dy = t/3, dx = t%3;
        int ci = c2*32 + kl;
        val = w[((size_t)(co*Ci + ci)*3 + dy)*3 + dx];
    } else {
        int dy = kc >> 1, half = kc & 1;
        int dx = half*2 + (kl >> 4);
        int ci = kl & 15;
        if (dx < 3) val = w[((size_t)(co*Ci + ci)*3 + dy)*3 + dx];
    }
    wt[idx] = __float2bfloat16(val);
}

// ---------------------------------------------------------------------------
// One setup dispatch: BUF1/BUF2 border zero + 4 weight transforms + acc=0.
// Segment offsets: zb32 24704 | zb16 12352 | wt1 18432 | wt2 4608 | wt3 6144
// | wt4 18432 -> total 84672 items.
// ---------------------------------------------------------------------------
__global__ __launch_bounds__(256)
void setup_kernel(const float* __restrict__ w1, const float* __restrict__ w2,
                  const float* __restrict__ w3, const float* __restrict__ w4,
                  __hip_bfloat16* WT1, __hip_bfloat16* WT2,
                  __hip_bfloat16* WT3, __hip_bfloat16* WT4,
                  __hip_bfloat16* BUF1, __hip_bfloat16* BUF2,
                  float* acc)
{
    int idx = blockIdx.x*256 + threadIdx.x;
    if (idx == 0) *acc = 0.f;
    if      (idx < 24704) zb_item<32>(BUF1, idx);
    else if (idx < 37056) zb_item<16>(BUF2, idx - 24704);
    else if (idx < 55488) wt_item<64,32>(w1, WT1, idx - 37056);
    else if (idx < 60096) wt_item<32,16>(w2, WT2, idx - 55488);
    else if (idx < 66240) wt_item<16,32>(w3, WT3, idx - 60096);
    else if (idx < 84672) wt_item<32,64>(w4, WT4, idx - 66240);
}

// fused_feat = 0.5*(feat0+feat1) exactly (the m-softmax collapses to 1/2).
// Fallback only (scratch couldn't move off d_out -> can't fuse into conv4).
__global__ __launch_bounds__(256)
void fused_avg_kernel(const float4* __restrict__ a, const float4* __restrict__ b,
                      float4* __restrict__ o, int n4)
{
    int i = blockIdx.x*256 + threadIdx.x;
    if (i < n4) {
        float4 x = a[i], y = b[i];
        float4 r;
        r.x = 0.5f*(x.x + y.x);
        r.y = 0.5f*(x.y + y.y);
        r.z = 0.5f*(x.z + y.z);
        r.w = 0.5f*(x.w + y.w);
        o[i] = r;
    }
}

extern "C" void kernel_launch(void* const* d_in, const int* in_sizes, int n_in,
                              void* d_out, int out_size, void* d_ws, size_t ws_size,
                              hipStream_t stream)
{
    const float* feat0 = (const float*)d_in[0];
    const float* feat1 = (const float*)d_in[1];
    const float* w1 = (const float*)d_in[2];
    const float* b1 = (const float*)d_in[3];
    const float* w2 = (const float*)d_in[4];
    const float* b2 = (const float*)d_in[5];
    const float* w3 = (const float*)d_in[6];
    const float* b3 = (const float*)d_in[7];
    const float* w4 = (const float*)d_in[8];
    const float* b4 = (const float*)d_in[9];

    float* out = (float*)d_out;
    float* acc = out + NPIX;                 // loss output slot

    // Scratch layout (TF eliminated; total 25,853,952 B):
    //   BUF1 32ch padded NHWC @ 0        (17,172,480)
    //   BUF2 16ch padded NHWC @ 17172480 ( 8,586,240)
    //   WT1 @ 25758720 (36,864) | WT2 @ 25795584 (9,216)
    //   WT3 @ 25804800 (12,288) | WT4 @ 25817088 (36,864)
    constexpr size_t SCR_SZ = 25853952;
    const bool use_ws = (d_ws != nullptr) && (ws_size >= SCR_SZ);
    char* sb = use_ws ? (char*)d_ws : (char*)d_out;  // fallback: out written last

    __hip_bfloat16* BUF1 = (__hip_bfloat16*)(sb + 0);
    __hip_bfloat16* BUF2 = (__hip_bfloat16*)(sb + 17172480);
    __hip_bfloat16* WT1  = (__hip_bfloat16*)(sb + 25758720);
    __hip_bfloat16* WT2  = (__hip_bfloat16*)(sb + 25795584);
    __hip_bfloat16* WT3  = (__hip_bfloat16*)(sb + 25804800);
    __hip_bfloat16* WT4  = (__hip_bfloat16*)(sb + 25817088);

    setup_kernel<<<331, 256, 0, stream>>>(w1, w2, w3, w4,
                                          WT1, WT2, WT3, WT4, BUF1, BUF2, acc);

    dim3 cgrid(W_/64, H_/4, B_);      // 1024 blocks
    dim3 blk(256);

    const float* feats[2] = { feat0, feat1 };
    for (int m = 0; m < 2; ++m) {
        conv_mfma<64,32,false,true ,false><<<cgrid, blk, 0, stream>>>(
            feats[m], WT1, b1, BUF1, nullptr, nullptr, nullptr, nullptr);
        conv_mfma<32,16,false,false,false><<<cgrid, blk, 0, stream>>>(
            BUF1, WT2, b2, BUF2, nullptr, nullptr, nullptr, nullptr);
        conv_mfma<16,32,false,false,false><<<cgrid, blk, 0, stream>>>(
            BUF2, WT3, b3, BUF1, nullptr, nullptr, nullptr, nullptr);
        if (m == 1 && use_ws)
            conv_mfma<32,64,true ,false,true ><<<cgrid, blk, 0, stream>>>(
                BUF1, WT4, b4, nullptr, feats[1], feats[0], out, acc);
        else
            conv_mfma<32,64,true ,false,false><<<cgrid, blk, 0, stream>>>(
                BUF1, WT4, b4, nullptr, feats[m], nullptr, nullptr, acc);
    }

    if (!use_ws) {
        int n4 = NPIX/4;
        fused_avg_kernel<<<(n4 + 255)/256, 256, 0, stream>>>(
            (const float4*)feat0, (const float4*)feat1, (float4*)out, n4);
    }
}

// Round 2
// 317.695 us; speedup vs baseline: 1.1925x; 1.0731x over previous
//
#include <hip/hip_runtime.h>
#include <hip/hip_bf16.h>

#define B_ 8
#define H_ 128
#define W_ 256
#define PH 130          // H + 2 zero-pad rows
#define PW 258          // W + 2 zero-pad cols
#define NPIX (B_*64*H_*W_)

typedef short short8  __attribute__((ext_vector_type(8)));  // 8 bf16 (4 VGPRs)
typedef short short4v __attribute__((ext_vector_type(4)));  // 4 bf16 (8 B)
typedef float floatx4 __attribute__((ext_vector_type(4)));  // MFMA C/D

// ---------------------------------------------------------------------------
// Implicit-GEMM 3x3 SAME conv + bias + ReLU, bf16 MFMA 16x16x32, LDS-staged.
// Block = 256 thr = 4 waves; 4 output rows x 64 px x all Co. Wave r owns row.
// R6 changes vs R5:
//  * MODALITY-MERGED dispatches: grid z = 2*B_ (mz = z>>3, bz = z&7). Both
//    independent conv chains run in ONE dispatch -> 2x resident blocks,
//    ~half the fill/drain cost, 4 fewer launch gaps. AVG is runtime mz==1.
//  * conv1 Ci-SPLIT staging: two {stage 32ch, mfma} phases. Slab 50.7->25.4KB
//    -> 6 blocks/CU (was 3). Stage loop wave-per-chunk, fully unrolled 7
//    iters -> 56 co-live channel-strided fp32 loads per lane.
// ---------------------------------------------------------------------------
template<int Ci, int Co, bool LOSS, bool NCHW_IN, bool AVG>
__global__ __launch_bounds__(256)
void conv_mfma(const void* __restrict__ inA,    // m0 input (bf16 NHWC / fp32 NCHW)
               const void* __restrict__ inB,    // m1 input
               const __hip_bfloat16* __restrict__ wt,   // [KC][Co][32] bf16
               const float* __restrict__ bias,
               __hip_bfloat16* __restrict__ outp,       // padded NHWC per-m
               size_t out_mstride,                      // bf16 elems between m
               const float* __restrict__ ref0,          // fp32 NCHW (LOSS)
               const float* __restrict__ ref1,
               const float* __restrict__ other,         // feat0 (AVG, m1 only)
               float* __restrict__ avg_out,             // fused out (AVG)
               float* __restrict__ acc_out)
{
    constexpr int CC   = (Ci >= 32) ? Ci/32 : 1;
    constexpr int SCI  = NCHW_IN ? 32 : Ci;        // channels resident in slab
    constexpr int PXB  = SCI*2;                    // bytes per pixel in slab
    constexpr int NCB  = PXB/16;                   // 16B chunks per pixel
    constexpr int SLAB = 6*66*PXB;
    constexpr int NT   = Co/16;
    constexpr int GNT  = (NT >= 2) ? 2 : 1;        // nt-tiles per B-batch
    constexpr int NG   = NT / GNT;
    constexpr int EPIW = 64*(Co+8)*2;              // per-wave epilogue tile
    constexpr int RECB = 64*272*2;                 // LOSS rec tile [64co][4row][68px]
    constexpr int LDSZ = LOSS ? (RECB > SLAB ? RECB : SLAB)
                              : (4*EPIW > SLAB ? 4*EPIW : SLAB);
    __shared__ alignas(16) char slab[LDSZ + 32];
    __shared__ float wred[4];

    const int tid  = threadIdx.x;
    const int lane = tid & 63;
    const int wid  = tid >> 6;
    const int col  = lane & 15;
    const int quad = lane >> 4;
    const int w0   = blockIdx.x * 64;
    const int h0   = blockIdx.y * 4;
    const int zz   = blockIdx.z;
    const int bz   = zz & 7;
    const int mz   = zz >> 3;
    const int r    = wid;

    floatx4 acc[4][NT];
#pragma unroll
    for (int mt = 0; mt < 4; ++mt)
#pragma unroll
        for (int nt = 0; nt < NT; ++nt)
            acc[mt][nt] = (floatx4)0.f;

    // ---- per-c2 MFMA phase over the slab (slab holds SCI channels).
    auto mfma_c2 = [&](int c2) {
#pragma unroll
        for (int g = 0; g < NG; ++g) {
            short8 bfr[9*GNT];     // batched independent B loads
#pragma unroll
            for (int t = 0; t < 9; ++t)
#pragma unroll
                for (int j = 0; j < GNT; ++j)
                    bfr[t*GNT+j] = *(const short8*)(wt
                        + ((size_t)(c2*9+t)*Co + (g*GNT+j)*16 + col)*32 + quad*8);
#pragma unroll
            for (int t = 0; t < 9; ++t) {
                const int dy = t/3, dx = t - (t/3)*3;
                short8 a[4];
#pragma unroll
                for (int mt = 0; mt < 4; ++mt) {
                    int px  = (r+dy)*66 + mt*16 + col + dx;
                    int kch = NCHW_IN ? quad : (c2*4 + quad);
                    a[mt] = *(const short8*)(slab + px*PXB
                              + ((kch ^ (px & (NCB-1))) << 4));
                }
#pragma unroll
                for (int j = 0; j < GNT; ++j)
#pragma unroll
                    for (int mt = 0; mt < 4; ++mt)
                        acc[mt][g*GNT+j] = __builtin_amdgcn_mfma_f32_16x16x32_bf16(
                            a[mt], bfr[t*GNT+j], acc[mt][g*GNT+j], 0, 0, 0);
            }
        }
    };

    if constexpr (NCHW_IN) {
        // ---- fp32 NCHW feat, split into CC {stage 32ch, compute} phases.
        // Wave wid owns channel-chunk cb=wid (8 ch). Lanes = consecutive px
        // (coalesced fp32 runs). Zero-pad border via clamped-addr + select.
        static_assert(Ci == 64, "NCHW staging is Ci=64 only");
        const float* src = (const float*)(mz ? inB : inA) + (size_t)bz * 64 * H_ * W_;
#pragma unroll
        for (int c2 = 0; c2 < CC; ++c2) {
            if (c2) __syncthreads();             // prior-phase reads done
            const float* chb = src + (size_t)(c2*32 + wid*8) * (H_*W_);
#pragma unroll
            for (int it = 0; it < 7; ++it) {
                int pxl = it*64 + lane;          // 0..395 live (6 rows x 66)
                bool live = (it < 6) || (lane < 12);
                int row = pxl / 66;
                int pxc = pxl - row*66;
                int gh  = h0 + row - 1;
                int gw  = w0 + pxc - 1;
                bool ok = live && ((unsigned)gh < (unsigned)H_)
                               && ((unsigned)gw < (unsigned)W_);
                const float* sp = chb + (size_t)(ok ? gh : 0)*W_ + (ok ? gw : 0);
                short8 v;
#pragma unroll
                for (int j = 0; j < 8; ++j) {
                    float f = sp[(size_t)j*(H_*W_)];
                    v[j] = __builtin_bit_cast(short, __float2bfloat16(ok ? f : 0.f));
                }
                if (live)
                    *(short8*)(slab + pxl*PXB + ((wid ^ (pxl & (NCB-1))) << 4)) = v;
            }
            __syncthreads();
            mfma_c2(c2);
        }
    } else {
        // ---- stage slab from padded bf16 NHWC: coalesced 16B chunks.
        const __hip_bfloat16* inb = (const __hip_bfloat16*)(mz ? inB : inA)
                                    + (size_t)bz * PH * PW * Ci;
        for (int o = tid*16; o < SLAB; o += 4096) {
            int pxl = o / PXB;
            int row = pxl / 66;
            int pxc = pxl - row*66;
            int cb  = (o >> 4) & (NCB-1);
            short8 v = *(const short8*)(inb + ((size_t)(h0+row)*PW + (w0+pxc))*Ci + cb*8);
            *(short8*)(slab + pxl*PXB + ((cb ^ (pxl & (NCB-1))) << 4)) = v;
        }
        __syncthreads();

        if constexpr (Ci >= 32) {
#pragma unroll
            for (int c2 = 0; c2 < CC; ++c2)
                mfma_c2(c2);
        } else {
            // Ci=16: K=32 packs 2 dx taps; half1 upper quads carry zero weights.
            short8 bfr[6*NT];
#pragma unroll
            for (int kc = 0; kc < 6; ++kc)
#pragma unroll
                for (int j = 0; j < NT; ++j)
                    bfr[kc*NT+j] = *(const short8*)(wt
                        + ((size_t)kc*Co + j*16 + col)*32 + quad*8);
#pragma unroll
            for (int kc = 0; kc < 6; ++kc) {
                const int dy = kc >> 1, half = kc & 1;
                const int dxe = half ? 2 : (quad >> 1);
                short8 a[4];
#pragma unroll
                for (int mt = 0; mt < 4; ++mt) {
                    int px = (r+dy)*66 + mt*16 + col + dxe;
                    a[mt] = *(const short8*)(slab + px*PXB
                              + (((quad & 1) ^ (px & 1)) << 4));
                }
#pragma unroll
                for (int j = 0; j < NT; ++j)
#pragma unroll
                    for (int mt = 0; mt < 4; ++mt)
                        acc[mt][j] = __builtin_amdgcn_mfma_f32_16x16x32_bf16(
                            a[mt], bfr[kc*NT+j], acc[mt][j], 0, 0, 0);
            }
        }
    }

    if constexpr (!LOSS) {
        __syncthreads();
        char* rt = slab + wid * EPIW;     // per-wave [64 px][Co+8] bf16 tile
#pragma unroll
        for (int nt = 0; nt < NT; ++nt) {
            float bv = bias[nt*16 + col];
#pragma unroll
            for (int mt = 0; mt < 4; ++mt) {
#pragma unroll
                for (int rr = 0; rr < 4; ++rr) {
                    float v = acc[mt][nt][rr] + bv;
                    v = v > 0.f ? v : 0.f;
                    int px = mt*16 + quad*4 + rr;
                    *(__hip_bfloat16*)(rt + (px*(Co+8) + nt*16 + col)*2) =
                        __float2bfloat16(v);
                }
            }
        }
        __hip_bfloat16* ob = outp + (size_t)mz * out_mstride;
        char* grow = (char*)ob
            + (((size_t)bz*PH + (h0 + r + 1))*PW + (w0 + 1))*Co*2;
        constexpr int GB = 64*Co*2;
#pragma unroll
        for (int id = 0; id < GB/1024; ++id) {
            int o  = id*1024 + lane*16;
            int px = o / (Co*2);
            int cb = o - px*(Co*2);
            *(short8*)(grow + o) = *(const short8*)(rt + px*(Co+8)*2 + cb);
        }
    } else {
        // ---- rec -> LDS bf16 [co][row][68] (b64-aligned), barriered
        __syncthreads();                        // all slab reads complete
        __hip_bfloat16* rec = (__hip_bfloat16*)slab;
#pragma unroll
        for (int nt = 0; nt < NT; ++nt) {
            int co = nt*16 + col;
            float bv = bias[co];
#pragma unroll
            for (int mt = 0; mt < 4; ++mt) {
                short4v pk;
#pragma unroll
                for (int rr = 0; rr < 4; ++rr) {
                    float v = acc[mt][nt][rr] + bv;
                    v = v > 0.f ? v : 0.f;
                    pk[rr] = __builtin_bit_cast(short, __float2bfloat16(v));
                }
                *(short4v*)(rec + co*272 + r*68 + mt*16 + quad*4) = pk;
            }
        }
        __syncthreads();

        // ---- coalesced fp32 ref compare: 16 iters, 256B contiguous per co.
        // AVG (m1 only): same tile addresses -> fused = 0.5*(f0+f1).
        float lsum = 0.f;
        const float* refb = (mz ? ref1 : ref0) + (size_t)bz * 64 * H_ * W_;
#pragma unroll
        for (int i = 0; i < 16; ++i) {
            int row = i & 3, cg = i >> 2;
            int co  = cg*16 + wid*4 + quad;
            size_t off = ((size_t)co*H_ + h0 + row)*W_ + w0 + col*4;
            float4 f = *(const float4*)(refb + off);
            short4v pk = *(const short4v*)(rec + co*272 + row*68 + col*4);
            float d0 = f.x - __bfloat162float(__builtin_bit_cast(__hip_bfloat16, pk[0]));
            float d1 = f.y - __bfloat162float(__builtin_bit_cast(__hip_bfloat16, pk[1]));
            float d2 = f.z - __bfloat162float(__builtin_bit_cast(__hip_bfloat16, pk[2]));
            float d3 = f.w - __bfloat162float(__builtin_bit_cast(__hip_bfloat16, pk[3]));
            lsum += d0*d0 + d1*d1 + d2*d2 + d3*d3;
            if constexpr (AVG) {
                if (mz) {
                    const float* othb = other + (size_t)bz * 64 * H_ * W_;
                    float*       avgb = avg_out + (size_t)bz * 64 * H_ * W_;
                    float4 g = *(const float4*)(othb + off);
                    float4 o;
                    o.x = 0.5f*(f.x + g.x);
                    o.y = 0.5f*(f.y + g.y);
                    o.z = 0.5f*(f.z + g.z);
                    o.w = 0.5f*(f.w + g.w);
                    *(float4*)(avgb + off) = o;
                }
            }
        }
#pragma unroll
        for (int off = 32; off > 0; off >>= 1)
            lsum += __shfl_down(lsum, off, 64);
        if (lane == 0) wred[wid] = lsum;
        __syncthreads();
        if (tid == 0)      // 1/NPIX = 2^-24 exact: fold finalize into the atomic
            atomicAdd(acc_out, (wred[0] + wred[1] + wred[2] + wred[3])
                               * (1.0f / (float)NPIX));
    }
}

// ---------------------------------------------------------------------------
// Border-zero work item: pad cells of a padded NHWC buffer (772 px / image).
// img range may span both modalities (buffers are contiguous).
// ---------------------------------------------------------------------------
template<int C>
__device__ __forceinline__ void zb_item(__hip_bfloat16* buf, int idx)
{
    constexpr int CP = C/8;
    int cb   = idx % CP;
    int cell = (idx / CP) % 772;
    int img  = idx / (CP*772);
    int row, colp;
    if (cell < 258)      { row = 0;   colp = cell; }
    else if (cell < 516) { row = 129; colp = cell - 258; }
    else { int r2 = cell - 516; row = 1 + (r2 >> 1); colp = (r2 & 1) ? 257 : 0; }
    short8 z = (short8)0;
    *(short8*)(buf + (((size_t)img*PH + row)*PW + colp)*C + cb*8) = z;
}

// ---------------------------------------------------------------------------
// OIHW fp32 -> [KC][Co][32] bf16 B-operand work item. Ci>=32: kc = c2*9 + tap.
// Ci=16: kc = dy*2+half; dx slot 3 = zero.
// ---------------------------------------------------------------------------
template<int Ci, int Co>
__device__ __forceinline__ void wt_item(const float* __restrict__ w,
                                        __hip_bfloat16* __restrict__ wt, int idx)
{
    int kl = idx & 31;
    int co = (idx >> 5) % Co;
    int kc = idx / (32*Co);
    float val = 0.f;
    if constexpr (Ci >= 32) {
        int c2 = kc / 9, t = kc % 9;
        int dy = t/3, dx = t%3;
        int ci = c2*32 + kl;
        val = w[((size_t)(co*Ci + ci)*3 + dy)*3 + dx];
    } else {
        int dy = kc >> 1, half = kc & 1;
        int dx = half*2 + (kl >> 4);
        int ci = kl & 15;
        if (dx < 3) val = w[((size_t)(co*Ci + ci)*3 + dy)*3 + dx];
    }
    wt[idx] = __float2bfloat16(val);
}

// ---------------------------------------------------------------------------
// One setup dispatch: BUF1/BUF2 (both modalities) border zero + 4 weight
// transforms + acc=0. Segments: zb32 49408 | zb16 24704 | wt1 18432 |
// wt2 4608 | wt3 6144 | wt4 18432 -> total 121728 items.
// ---------------------------------------------------------------------------
__global__ __launch_bounds__(256)
void setup_kernel(const float* __restrict__ w1, const float* __restrict__ w2,
                  const float* __restrict__ w3, const float* __restrict__ w4,
                  __hip_bfloat16* WT1, __hip_bfloat16* WT2,
                  __hip_bfloat16* WT3, __hip_bfloat16* WT4,
                  __hip_bfloat16* BUF1, __hip_bfloat16* BUF2,
                  float* acc)
{
    int idx = blockIdx.x*256 + threadIdx.x;
    if (idx == 0) *acc = 0.f;
    if      (idx <  49408) zb_item<32>(BUF1, idx);
    else if (idx <  74112) zb_item<16>(BUF2, idx - 49408);
    else if (idx <  92544) wt_item<64,32>(w1, WT1, idx - 74112);
    else if (idx <  97152) wt_item<32,16>(w2, WT2, idx - 92544);
    else if (idx < 103296) wt_item<16,32>(w3, WT3, idx - 97152);
    else if (idx < 121728) wt_item<32,64>(w4, WT4, idx - 103296);
}

// fused_feat = 0.5*(feat0+feat1) exactly (the m-softmax collapses to 1/2).
// Fallback only (scratch couldn't move off d_out -> can't fuse into conv4).
__global__ __launch_bounds__(256)
void fused_avg_kernel(const float4* __restrict__ a, const float4* __restrict__ b,
                      float4* __restrict__ o, int n4)
{
    int i = blockIdx.x*256 + threadIdx.x;
    if (i < n4) {
        float4 x = a[i], y = b[i];
        float4 r;
        r.x = 0.5f*(x.x + y.x);
        r.y = 0.5f*(x.y + y.y);
        r.z = 0.5f*(x.z + y.z);
        r.w = 0.5f*(x.w + y.w);
        o[i] = r;
    }
}

extern "C" void kernel_launch(void* const* d_in, const int* in_sizes, int n_in,
                              void* d_out, int out_size, void* d_ws, size_t ws_size,
                              hipStream_t stream)
{
    const float* feat0 = (const float*)d_in[0];
    const float* feat1 = (const float*)d_in[1];
    const float* w1 = (const float*)d_in[2];
    const float* b1 = (const float*)d_in[3];
    const float* w2 = (const float*)d_in[4];
    const float* b2 = (const float*)d_in[5];
    const float* w3 = (const float*)d_in[6];
    const float* b3 = (const float*)d_in[7];
    const float* w4 = (const float*)d_in[8];
    const float* b4 = (const float*)d_in[9];

    float* out = (float*)d_out;
    float* acc = out + NPIX;                 // loss output slot

    // Scratch layout, per-modality buffers contiguous (total 51,612,672 B):
    //   BUF1[2] 32ch padded NHWC @ 0         (2 x 17,172,480)
    //   BUF2[2] 16ch padded NHWC @ 34344960  (2 x  8,586,240)
    //   WT1 @ 51517440 (36,864) | WT2 @ 51554304 (9,216)
    //   WT3 @ 51563520 (12,288) | WT4 @ 51575808 (36,864)
    constexpr size_t B1B = (size_t)B_*PH*PW*32*2;    // 17,172,480 bytes
    constexpr size_t B2B = (size_t)B_*PH*PW*16*2;    //  8,586,240 bytes
    constexpr size_t SCR_SZ = 51612672;
    const bool use_ws = (d_ws != nullptr) && (ws_size >= SCR_SZ);
    char* sb = use_ws ? (char*)d_ws : (char*)d_out;  // fallback: out written last

    __hip_bfloat16* BUF1 = (__hip_bfloat16*)(sb + 0);
    __hip_bfloat16* BUF2 = (__hip_bfloat16*)(sb + 2*B1B);
    __hip_bfloat16* WT1  = (__hip_bfloat16*)(sb + 51517440);
    __hip_bfloat16* WT2  = (__hip_bfloat16*)(sb + 51554304);
    __hip_bfloat16* WT3  = (__hip_bfloat16*)(sb + 51563520);
    __hip_bfloat16* WT4  = (__hip_bfloat16*)(sb + 51575808);

    setup_kernel<<<476, 256, 0, stream>>>(w1, w2, w3, w4,
                                          WT1, WT2, WT3, WT4, BUF1, BUF2, acc);

    dim3 cgrid(W_/64, H_/4, 2*B_);    // 2048 blocks: both modalities
    dim3 blk(256);

    constexpr size_t B1E = B1B/2;     // bf16-element modality strides
    constexpr size_t B2E = B2B/2;

    conv_mfma<64,32,false,true ,false><<<cgrid, blk, 0, stream>>>(
        feat0, feat1, WT1, b1, BUF1, B1E,
        nullptr, nullptr, nullptr, nullptr, nullptr);
    conv_mfma<32,16,false,false,false><<<cgrid, blk, 0, stream>>>(
        BUF1, BUF1 + B1E, WT2, b2, BUF2, B2E,
        nullptr, nullptr, nullptr, nullptr, nullptr);
    conv_mfma<16,32,false,false,false><<<cgrid, blk, 0, stream>>>(
        BUF2, BUF2 + B2E, WT3, b3, BUF1, B1E,
        nullptr, nullptr, nullptr, nullptr, nullptr);
    if (use_ws)
        conv_mfma<32,64,true ,false,true ><<<cgrid, blk, 0, stream>>>(
            BUF1, BUF1 + B1E, WT4, b4, nullptr, 0,
            feat0, feat1, feat0, out, acc);
    else {
        conv_mfma<32,64,true ,false,false><<<cgrid, blk, 0, stream>>>(
            BUF1, BUF1 + B1E, WT4, b4, nullptr, 0,
            feat0, feat1, nullptr, nullptr, acc);
        int n4 = NPIX/4;
        fused_avg_kernel<<<(n4 + 255)/256, 256, 0, stream>>>(
            (const float4*)feat0, (const float4*)feat1, (float4*)out, n4);
    }
}